// Round 4
// baseline (312.436 us; speedup 1.0000x reference)
//
#include <hip/hip_runtime.h>
#include <hip/hip_fp16.h>

#define NBINS 255
#define NPAIRS 32
#define BIGF 3.0e38f

// ws layout (float index):
//   [0     ,16384) : E    [64][256] fp32 edges, tail BIGF
//   [16384 ,32768) : PE   [64][256]
//   [32768 ,36864) : G    [64][256] ushort grid: lo byte = unary g0, hi = pair g0
//   [43008 ,51200) : W16g [64][256] fp16 PRE-SHIFTED
//   byte 204800 .. : T16  [32][256][256] fp16 PRE-SHIFTED (needs ws >= 4399104 B)
//
// g0[f][cell] = #{fine-group boundaries B[g]=edges[f][4g+3], g<63 : cellOf(B) < cell}
// -> lower bound of the true fine-group index for any x with cellOf(x)=cell.
// True group is g0 (+1 if x >= B[g0]) (+rare exec-masked loop, exact for any data).

__device__ __forceinline__ int cell_of(float x) {
    // monotone CDF-approx: u = sigmoid(1.702x) = rcp(1 + 2^(-2.4567x)).
    // HW v_exp/v_rcp are deterministic -> identical in prep and main.
    float h = __builtin_amdgcn_exp2f(-2.4567f * x);
    float u = __builtin_amdgcn_rcpf(1.0f + h);
    int c = (int)(u * 256.0f);
    c = c < 0 ? 0 : c;
    c = c > 255 ? 255 : c;
    return c;
}

__global__ void ebm_prep(const float* __restrict__ edges,
                         const float* __restrict__ pair_edges,
                         const float* __restrict__ w,
                         float* __restrict__ ws) {
    int f = blockIdx.x, j = threadIdx.x;   // 64 blocks x 256 threads
    float* E  = ws;
    float* PE = ws + 16384;
    unsigned short* G = (unsigned short*)(ws + 32768);
    __half* W = (__half*)(ws + 43008);
    E[f * 256 + j]  = (j < NBINS) ? edges[f * NBINS + j]      : BIGF;
    PE[f * 256 + j] = (j < NBINS) ? pair_edges[f * NBINS + j] : BIGF;
    int src = (j < 255) ? j + 1 : 0;
    W[f * 256 + j]  = __float2half(w[f * 256 + src]);

    __shared__ int bu[63], bp[63];
    if (j < 63) {
        bu[j] = cell_of(edges[f * NBINS + 4 * j + 3]);       // 4j+3 <= 251 < 255
        bp[j] = cell_of(pair_edges[f * NBINS + 4 * j + 3]);
    }
    __syncthreads();
    int gu = 0, gp = 0;
#pragma unroll
    for (int g = 0; g < 63; ++g) { gu += (bu[g] < j); gp += (bp[g] < j); }
    G[f * 256 + j] = (unsigned short)(gu | (gp << 8));
}

__global__ void ebm_prep_tables(const float* __restrict__ tables,
                                unsigned short* __restrict__ o) {
    int i = blockIdx.x * blockDim.x + threadIdx.x;    // 2097152 threads
    int b = i & 255, a = (i >> 8) & 255, p = i >> 16;
    int ra = (a < 255) ? a + 1 : 0;
    int rb = (b < 255) ? b + 1 : 0;
    o[i] = __half_as_ushort(__float2half(tables[(p << 16) + (ra << 8) + rb]));
}

// uniform 16-way register select: s is wave-uniform -> 15 v_cndmask w/ scalar masks
__device__ __forceinline__ unsigned pick16(const unsigned* pw, int s) {
    unsigned v01 = (s & 1) ? pw[1]  : pw[0];
    unsigned v23 = (s & 1) ? pw[3]  : pw[2];
    unsigned v45 = (s & 1) ? pw[5]  : pw[4];
    unsigned v67 = (s & 1) ? pw[7]  : pw[6];
    unsigned v89 = (s & 1) ? pw[9]  : pw[8];
    unsigned vab = (s & 1) ? pw[11] : pw[10];
    unsigned vcd = (s & 1) ? pw[13] : pw[12];
    unsigned vef = (s & 1) ? pw[15] : pw[14];
    unsigned w0 = (s & 2) ? v23 : v01;
    unsigned w1 = (s & 2) ? v67 : v45;
    unsigned w2 = (s & 2) ? vab : v89;
    unsigned w3 = (s & 2) ? vef : vcd;
    unsigned u0 = (s & 4) ? w1 : w0;
    unsigned u1 = (s & 4) ? w3 : w2;
    return (s & 8) ? u1 : u0;
}

// v5: coarse+mid levels replaced by inverse-CDF grid lookup (pure-DS lgkm
// domain, no s_loads in loop, ~half the VALU). LDS = fine(128K) + grid(32K).
__global__ __launch_bounds__(1024, 4) void ebm_main(
    const float* __restrict__ x,
    const int*   __restrict__ pairs,
    const float* __restrict__ tables_f32,
    const float* __restrict__ bias,
    const float* __restrict__ ws,
    const __half* __restrict__ T16,
    int useT16,
    float*       __restrict__ out) {

    // exactly 160 KiB
    __shared__ float  sE[16384];            // unary fine [64][64] float4
    __shared__ float  sPE[16384];           // pair  fine
    __shared__ unsigned short sG[16384];    // grid [64][256] packed u8 pair

    int tid = threadIdx.x;
    {
        const float4* w4 = (const float4*)ws;
        float4* dE = (float4*)sE;
        float4* dP = (float4*)sPE;
        float4* dG = (float4*)sG;
        for (int i = tid; i < 4096; i += 1024) {
            dE[i] = w4[i];
            dP[i] = w4[4096 + i];
        }
        for (int i = tid; i < 2048; i += 1024) dG[i] = w4[8192 + i];
    }
    const __half* Wg = (const __half*)(ws + 43008);
    float bias0 = bias[0];

    __syncthreads();

    int row = blockIdx.x * 1024 + tid;       // 256 blocks x 1024 threads
    const float4* x4  = (const float4*)x + row * 16;
    const float4* sE4 = (const float4*)sE;
    const float4* sP4 = (const float4*)sPE;

    float acc = 0.f;
    unsigned pw[16];

    float4 xa = x4[0];
    float4 xb = x4[1];
#pragma unroll
    for (int gg = 0; gg < 8; ++gg) {
        int fb = gg * 8;                      // feature base (compile-time)
        float4 xan = xa, xbn = xb;
        if (gg < 7) { xan = x4[2 * gg + 2]; xbn = x4[2 * gg + 3]; }
        float xf[8] = {xa.x, xa.y, xa.z, xa.w, xb.x, xb.y, xb.z, xb.w};

        // ---- grid lookup: 8 cells -> 8 ds_read_u16 ----
        unsigned gw[8];
#pragma unroll
        for (int j = 0; j < 8; ++j) {
            int cell = cell_of(xf[j]);
            gw[j] = sG[(fb + j) * 256 + cell];
        }

        unsigned p0 = 0, p1 = 0;
#pragma unroll
        for (int j = 0; j < 8; ++j) {
            float xv = xf[j];
            int g0u = gw[j] & 255;
            int g0p = gw[j] >> 8;
            int ebase = (fb + j) * 64;

            // unary: two contiguous fine groups, select, rare exact-loop
            float4 a0 = sE4[ebase + g0u];
            float4 a1 = sE4[ebase + g0u + 1];   // addr+offset:16; g0u=63 read unused (d=0, BIGF pad)
            bool du = xv >= a0.w;
            int gu2 = g0u + du;
            float4 fa = du ? a1 : a0;
            while (xv >= fa.w) { ++gu2; fa = sE4[ebase + gu2]; }   // exact, BIGF-terminated
            int c = 4 * gu2 + (xv >= fa.x) + (xv >= fa.y) + (xv >= fa.z);
            acc += __half2float(Wg[(fb + j) * 256 + c]);

            // pair: same structure
            float4 b0 = sP4[ebase + g0p];
            float4 b1 = sP4[ebase + g0p + 1];
            bool dp = xv >= b0.w;
            int gp2 = g0p + dp;
            float4 fpv = dp ? b1 : b0;
            while (xv >= fpv.w) { ++gp2; fpv = sP4[ebase + gp2]; }
            int c2 = 4 * gp2 + (xv >= fpv.x) + (xv >= fpv.y) + (xv >= fpv.z);
            if (j < 4) p0 |= (unsigned)c2 << (8 * j);
            else       p1 |= (unsigned)c2 << (8 * (j - 4));
        }
        pw[2 * gg]     = p0;
        pw[2 * gg + 1] = p1;
        xa = xan; xb = xbn;
    }

    // ---- pair table gathers: per-lane-owned, no exchange ----
    if (useT16) {
#pragma unroll
        for (int p = 0; p < NPAIRS; ++p) {
            int a = pairs[2 * p], b = pairs[2 * p + 1];   // uniform
            unsigned wa = pick16(pw, a >> 2);
            unsigned wb = pick16(pw, b >> 2);
            int li = (wa >> ((a & 3) * 8)) & 255;
            int ri = (wb >> ((b & 3) * 8)) & 255;
            acc += __half2float(T16[(p << 16) + (li << 8) + ri]);
        }
    } else {
#pragma unroll
        for (int p = 0; p < NPAIRS; ++p) {
            int a = pairs[2 * p], b = pairs[2 * p + 1];
            unsigned wa = pick16(pw, a >> 2);
            unsigned wb = pick16(pw, b >> 2);
            int li = (wa >> ((a & 3) * 8)) & 255;
            int ri = (wb >> ((b & 3) * 8)) & 255;
            int lb = (li < 255) ? li + 1 : 0;
            int rb = (ri < 255) ? ri + 1 : 0;
            acc += tables_f32[(p << 16) + (lb << 8) + rb];
        }
    }

    out[row] = 1.0f / (1.0f + __expf(-(acc + bias0)));
}

extern "C" void kernel_launch(void* const* d_in, const int* in_sizes, int n_in,
                              void* d_out, int out_size, void* d_ws, size_t ws_size,
                              hipStream_t stream) {
    const float* x          = (const float*)d_in[0];
    const float* edges      = (const float*)d_in[1];
    const float* w          = (const float*)d_in[2];
    const float* pair_edges = (const float*)d_in[3];
    const int*   pairs      = (const int*)d_in[4];
    const float* tables     = (const float*)d_in[5];
    const float* bias       = (const float*)d_in[6];
    float* out = (float*)d_out;
    float* ws  = (float*)d_ws;

    int useT16 = (ws_size >= (size_t)4399104) ? 1 : 0;
    __half* T16 = (__half*)((char*)d_ws + 204800);

    ebm_prep<<<64, 256, 0, stream>>>(edges, pair_edges, w, ws);
    if (useT16) {
        ebm_prep_tables<<<2048, 1024, 0, stream>>>(tables, (unsigned short*)T16);
    }
    ebm_main<<<256, 1024, 0, stream>>>(x, pairs, tables, bias, ws, T16, useT16, out);
}

// Round 5
// 200.737 us; speedup vs baseline: 1.5564x; 1.5564x over previous
//
#include <hip/hip_runtime.h>
#include <hip/hip_fp16.h>

#define NBINS 255
#define NPAIRS 32
#define BIGF 3.0e38f

// ws layout (float index):
//   [0     ,16384) : E    [64][256] fp32, tail BIGF
//   [16384 ,32768) : PE   [64][256]
//   [32768 ,36864) : M4E  [64][16] float4 {e[4j+3]} j=4t+c  (idx>=255 -> BIGF)
//   [36864 ,40960) : M4P
//   [40960 ,41984) : CU16 [64][16] coarse e[16j+15], j=15 pad BIGF
//   [41984 ,43008) : CP16
//   [43008 ,51200) : W16g [64][256] fp16 PRE-SHIFTED (8192 floats of storage)
//   byte 204800 .. : T16  [32][256][256] fp16 PRE-SHIFTED (needs ws >= 4399104 B)

__global__ void ebm_prep(const float* __restrict__ edges,
                         const float* __restrict__ pair_edges,
                         const float* __restrict__ w,
                         float* __restrict__ ws) {
    int tid = blockIdx.x * blockDim.x + threadIdx.x;  // 16384 threads
    int f = tid >> 8, j = tid & 255;
    float* E  = ws;
    float* PE = ws + 16384;
    float* ME = ws + 32768;
    float* MP = ws + 36864;
    float* CU = ws + 40960;
    float* CP = ws + 41984;
    __half* W = (__half*)(ws + 43008);
    E[tid]  = (j < NBINS) ? edges[f * NBINS + j]      : BIGF;
    PE[tid] = (j < NBINS) ? pair_edges[f * NBINS + j] : BIGF;
    int src = (j < 255) ? j + 1 : 0;
    W[tid]  = __float2half(w[f * 256 + src]);
    if (j < 64) {
        int idx = 4 * j + 3;   // j=4t+c -> e[16t+4c+3]
        ME[f * 64 + j] = (idx < NBINS) ? edges[f * NBINS + idx]      : BIGF;
        MP[f * 64 + j] = (idx < NBINS) ? pair_edges[f * NBINS + idx] : BIGF;
    }
    if (j < 16) {
        CU[f * 16 + j] = (j < 15) ? edges[f * NBINS + 16 * j + 15]      : BIGF;
        CP[f * 16 + j] = (j < 15) ? pair_edges[f * NBINS + 16 * j + 15] : BIGF;
    }
}

__global__ void ebm_prep_tables(const float* __restrict__ tables,
                                unsigned short* __restrict__ o) {
    int i = blockIdx.x * blockDim.x + threadIdx.x;    // 2097152 threads
    int b = i & 255, a = (i >> 8) & 255, p = i >> 16;
    int ra = (a < 255) ? a + 1 : 0;
    int rb = (b < 255) ? b + 1 : 0;
    o[i] = __half_as_ushort(__float2half(tables[(p << 16) + (ra << 8) + rb]));
}

// v6: v3 memory plan (all tables LDS, 160 KiB), but the main loop is an
// explicit 2-stage software pipeline over 16 x 4-wide batches:
//   (1) consume mids(g) -> issue fines(g)
//   (2) coarse(g+1)            [~240 VALU cycles covering fine latency]
//   (2b) issue mids(g+1)       [covered by steps 3-4]
//   (3) acc += W(g-1)          [vmcnt slack = one full batch]
//   (4) consume fines(g) -> issue W(g), pack pair byte
// Tail: pick16 (960 cndmask) replaced by pw -> LDS scratch (aliases sE after
// a barrier) + per-pair ds_read_u8; pairs fetched once per-lane + readlane.
__global__ __launch_bounds__(1024, 4) void ebm_main(
    const float* __restrict__ x,
    const int*   __restrict__ pairs,
    const float* __restrict__ tables_f32,
    const float* __restrict__ bias,
    const float* __restrict__ ws,
    const __half* __restrict__ T16,
    int useT16,
    float*       __restrict__ out) {

    // exactly 160 KiB
    __shared__ float  sE[16384];
    __shared__ float  sPE[16384];
    __shared__ float4 sME[1024];
    __shared__ float4 sMP[1024];

    int tid = threadIdx.x;
    int myab = pairs[tid & 63];            // lane l holds pairs[l]; used in tail via readlane
    {
        const float4* w4 = (const float4*)ws;
        float4* dE = (float4*)sE;
        float4* dP = (float4*)sPE;
        for (int i = tid; i < 4096; i += 1024) {
            dE[i] = w4[i];
            dP[i] = w4[4096 + i];
        }
        sME[tid] = w4[8192 + tid];
        sMP[tid] = w4[9216 + tid];
    }
    const float*  CU = ws + 40960;
    const float*  CP = ws + 41984;
    const __half* Wg = (const __half*)(ws + 43008);
    float bias0 = bias[0];

    __syncthreads();

    int row = blockIdx.x * 1024 + tid;       // 256 blocks x 1024 threads
    const float4* x4  = (const float4*)x + row * 16;
    const float4* sE4 = (const float4*)sE;
    const float4* sP4 = (const float4*)sPE;

    float acc = 0.f;
    unsigned pw[16];

    // ---- pipeline prologue: batch 0 coarse + mid issue ----
    float4 xa = x4[0];
    float4 xb = x4[1];
    float xf[4] = {xa.x, xa.y, xa.z, xa.w};
    int t[4], t2[4];
#pragma unroll
    for (int j = 0; j < 4; ++j) {
        const float* cu = CU + j * 16;       // uniform -> s_load
        int tt = 0;
#pragma unroll
        for (int k = 0; k < 15; ++k) tt += (xf[j] >= cu[k]);
        t[j] = tt;
    }
#pragma unroll
    for (int j = 0; j < 4; ++j) {
        const float* cp = CP + j * 16;
        int tt = 0;
#pragma unroll
        for (int k = 0; k < 15; ++k) tt += (xf[j] >= cp[k]);
        t2[j] = tt;
    }
    float4 mu[4], mp[4];
#pragma unroll
    for (int j = 0; j < 4; ++j) mu[j] = sME[j * 16 + t[j]];
#pragma unroll
    for (int j = 0; j < 4; ++j) mp[j] = sMP[j * 16 + t2[j]];

    __half wraw[4];
#pragma unroll
    for (int j = 0; j < 4; ++j) wraw[j] = __float2half(0.f);

#pragma unroll
    for (int g = 0; g < 16; ++g) {
        int fb = 4 * g;
        // (1) consume mids(g) -> lo; issue fines(g)
        int lo[4], lo2[4];
        float4 fu[4], fp[4];
#pragma unroll
        for (int j = 0; j < 4; ++j) {
            int m = (xf[j] >= mu[j].x) + (xf[j] >= mu[j].y) + (xf[j] >= mu[j].z);
            lo[j] = 4 * t[j] + m;
            fu[j] = sE4[(fb + j) * 64 + lo[j]];
        }
#pragma unroll
        for (int j = 0; j < 4; ++j) {
            int m = (xf[j] >= mp[j].x) + (xf[j] >= mp[j].y) + (xf[j] >= mp[j].z);
            lo2[j] = 4 * t2[j] + m;
            fp[j] = sP4[(fb + j) * 64 + lo2[j]];
        }
        // (2) coarse(g+1)
        float xfn[4] = {xb.x, xb.y, xb.z, xb.w};
        int tn[4] = {0, 0, 0, 0}, t2n[4] = {0, 0, 0, 0};
        if (g < 15) {
#pragma unroll
            for (int j = 0; j < 4; ++j) {
                const float* cu = CU + (fb + 4 + j) * 16;
                int tt = 0;
#pragma unroll
                for (int k = 0; k < 15; ++k) tt += (xfn[j] >= cu[k]);
                tn[j] = tt;
            }
#pragma unroll
            for (int j = 0; j < 4; ++j) {
                const float* cp = CP + (fb + 4 + j) * 16;
                int tt = 0;
#pragma unroll
                for (int k = 0; k < 15; ++k) tt += (xfn[j] >= cp[k]);
                t2n[j] = tt;
            }
        }
        // (2b) issue mids(g+1)
        float4 mun[4], mpn[4];
        if (g < 15) {
#pragma unroll
            for (int j = 0; j < 4; ++j) mun[j] = sME[(fb + 4 + j) * 16 + tn[j]];
#pragma unroll
            for (int j = 0; j < 4; ++j) mpn[j] = sMP[(fb + 4 + j) * 16 + t2n[j]];
        }
        // (3) deferred W adds from batch g-1
#pragma unroll
        for (int j = 0; j < 4; ++j) acc += __half2float(wraw[j]);
        // (4) consume fines(g): unary -> W issue; pair -> pack
#pragma unroll
        for (int j = 0; j < 4; ++j) {
            int c = 4 * lo[j] + (xf[j] >= fu[j].x) + (xf[j] >= fu[j].y) +
                    (xf[j] >= fu[j].z) + (xf[j] >= fu[j].w);
            wraw[j] = Wg[(fb + j) * 256 + c];
        }
        unsigned pword = 0;
#pragma unroll
        for (int j = 0; j < 4; ++j) {
            int c2 = 4 * lo2[j] + (xf[j] >= fp[j].x) + (xf[j] >= fp[j].y) +
                     (xf[j] >= fp[j].z) + (xf[j] >= fp[j].w);
            pword |= (unsigned)c2 << (8 * j);
        }
        pw[g] = pword;
        // rotate pipeline state (register renames under full unroll)
        if (g < 15) {
#pragma unroll
            for (int j = 0; j < 4; ++j) {
                xf[j] = xfn[j]; t[j] = tn[j]; t2[j] = t2n[j];
                mu[j] = mun[j]; mp[j] = mpn[j];
            }
            xa = xb;
            if (g < 14) xb = x4[g + 2];
        }
    }
#pragma unroll
    for (int j = 0; j < 4; ++j) acc += __half2float(wraw[j]);

    // ---- tail: pw -> LDS scratch (aliases sE), pair gathers via ds_read_u8 ----
    __syncthreads();                         // all fine-table reads complete
    unsigned* scr = (unsigned*)sE;           // [16][1024] words = 64 KiB exactly
#pragma unroll
    for (int i = 0; i < 16; ++i) scr[i * 1024 + tid] = pw[i];
    // each thread reads only its own words -> no barrier needed (in-order DS)
    const unsigned char* scrB = (const unsigned char*)sE;
    int boff = tid * 4;

    if (useT16) {
#pragma unroll
        for (int p = 0; p < NPAIRS; ++p) {
            int a = __builtin_amdgcn_readlane(myab, 2 * p);       // uniform
            int b = __builtin_amdgcn_readlane(myab, 2 * p + 1);
            int li = scrB[(a >> 2) * 4096 + boff + (a & 3)];
            int ri = scrB[(b >> 2) * 4096 + boff + (b & 3)];
            acc += __half2float(T16[(p << 16) + (li << 8) + ri]);
        }
    } else {
#pragma unroll
        for (int p = 0; p < NPAIRS; ++p) {
            int a = __builtin_amdgcn_readlane(myab, 2 * p);
            int b = __builtin_amdgcn_readlane(myab, 2 * p + 1);
            int li = scrB[(a >> 2) * 4096 + boff + (a & 3)];
            int ri = scrB[(b >> 2) * 4096 + boff + (b & 3)];
            int lb = (li < 255) ? li + 1 : 0;
            int rb = (ri < 255) ? ri + 1 : 0;
            acc += tables_f32[(p << 16) + (lb << 8) + rb];
        }
    }

    out[row] = 1.0f / (1.0f + __expf(-(acc + bias0)));
}

extern "C" void kernel_launch(void* const* d_in, const int* in_sizes, int n_in,
                              void* d_out, int out_size, void* d_ws, size_t ws_size,
                              hipStream_t stream) {
    const float* x          = (const float*)d_in[0];
    const float* edges      = (const float*)d_in[1];
    const float* w          = (const float*)d_in[2];
    const float* pair_edges = (const float*)d_in[3];
    const int*   pairs      = (const int*)d_in[4];
    const float* tables     = (const float*)d_in[5];
    const float* bias       = (const float*)d_in[6];
    float* out = (float*)d_out;
    float* ws  = (float*)d_ws;

    int useT16 = (ws_size >= (size_t)4399104) ? 1 : 0;
    __half* T16 = (__half*)((char*)d_ws + 204800);

    ebm_prep<<<64, 256, 0, stream>>>(edges, pair_edges, w, ws);
    if (useT16) {
        ebm_prep_tables<<<2048, 1024, 0, stream>>>(tables, (unsigned short*)T16);
    }
    ebm_main<<<256, 1024, 0, stream>>>(x, pairs, tables, bias, ws, T16, useT16, out);
}